// Round 10
// baseline (204.309 us; speedup 1.0000x reference)
//
#include <hip/hip_runtime.h>
#include <stdint.h>

#define S_LEN 4096
#define HDIM  768
#define NHEAD 12
#define DHEAD 64
#define NSPLIT 4

typedef _Float16 f16;
typedef __attribute__((ext_vector_type(8)))  _Float16 f16x8;
typedef __attribute__((ext_vector_type(4)))  _Float16 f16x4;
typedef __attribute__((ext_vector_type(4)))  float    f32x4;
typedef __attribute__((ext_vector_type(16))) float    f32x16;

typedef __attribute__((address_space(1))) void gv_t;
typedef __attribute__((address_space(3))) void lv_t;

__device__ __forceinline__ void async_copy16(const void* g, void* l) {
  __builtin_amdgcn_global_load_lds((gv_t*)g, (lv_t*)l, 16, 0, 0);
}

__device__ __forceinline__ float fast_exp2(float x) {
#if __has_builtin(__builtin_amdgcn_exp2f)
  return __builtin_amdgcn_exp2f(x);
#else
  return exp2f(x);
#endif
}

__device__ __forceinline__ int swz4(int row) { return (row ^ (row >> 2)) & 3; }

// ---------------- workspace layout (heavy reuse; ws >= 64 MB) ----------------
constexpr size_t OFF_META = 0;                          // int kcount
constexpr size_t OFF_POS  = 256;                        // int[4096]
constexpr size_t OFF_XB   = 65536;                      // f16 x[4096*768]
constexpr size_t SZ_XB    = (size_t)S_LEN * HDIM * 2;
constexpr size_t OFF_WQKV = OFF_XB + SZ_XB;             // f16[3*768*768]; later PL f32[4][12][4096]
constexpr size_t SZ_WQKV  = (size_t)3 * HDIM * HDIM * 2;
constexpr size_t OFF_WO   = OFF_WQKV + SZ_WQKV;         // f16[768*768]
constexpr size_t SZ_WO    = (size_t)HDIM * HDIM * 2;
constexpr size_t OFF_Q    = OFF_WO + SZ_WO;             // f16[12][4096][64]
constexpr size_t SZ_HD    = (size_t)NHEAD * S_LEN * DHEAD * 2;
constexpr size_t OFF_K    = OFF_Q + SZ_HD;              // f16[12][4096][64] compacted
constexpr size_t OFF_VT   = OFF_K + SZ_HD;              // f16[12][64][4096] transposed+permuted V
constexpr size_t OFF_VR   = OFF_VT + SZ_HD;             // f16[12][4096][64] V rows; later PO split0
constexpr size_t OFF_PO1  = OFF_VR + SZ_HD;             // PO splits 1..3 follow

// ---------------- prep: fp32->fp16 convert + mask compaction ----------------
__global__ __launch_bounds__(256) void k_prep(const float* __restrict__ x,
                                              const float* __restrict__ wq,
                                              const float* __restrict__ wk,
                                              const float* __restrict__ wv,
                                              const float* __restrict__ wo,
                                              const int* __restrict__ mi,
                                              f16* __restrict__ dst,
                                              int* __restrict__ pos,
                                              int* __restrict__ meta) {
  __shared__ int s_flag;
  __shared__ int s_cnt[256];
  const int b = blockIdx.x, tid = threadIdx.x;
  if (b < 5376) {
    int i = b * 256 + tid;                   // 1376256 float4 units
    const float* src; int off;
    if (i < 786432) { src = x; off = i; }
    else {
      int j = i - 786432;
      int w = j / 147456;
      off = j - w * 147456;
      src = (w == 0) ? wq : (w == 1) ? wk : (w == 2) ? wv : wo;
    }
    float4 v = ((const float4*)src)[off];
    f16x4 h;
    h[0] = (f16)v.x; h[1] = (f16)v.y; h[2] = (f16)v.z; h[3] = (f16)v.w;
    ((f16x4*)dst)[i] = h;
    return;
  }
  // ---- mask block ----
  if (tid == 0) s_flag = 1;
  __syncthreads();
  int bad = 0;
  #pragma unroll
  for (int k = 0; k < 4; ++k) {
    int v = mi[k * 256 + tid];
    if (v != 0 && v != 1) bad = 1;
  }
  if (bad) atomicAnd(&s_flag, 0);
  __syncthreads();
  const int isInt = s_flag;
  const unsigned char* mu8 = (const unsigned char*)mi;
  int keep[16]; int cnt = 0;
  const int s0 = tid * 16;
  #pragma unroll
  for (int k = 0; k < 16; ++k) {
    int mval = isInt ? mi[s0 + k] : (int)mu8[s0 + k];
    keep[k] = (mval == 0) ? 1 : 0;           // True => masked out (excluded)
    cnt += keep[k];
  }
  s_cnt[tid] = cnt;
  __syncthreads();
  for (int off = 1; off < 256; off <<= 1) {
    int t = (tid >= off) ? s_cnt[tid - off] : 0;
    __syncthreads();
    s_cnt[tid] += t;
    __syncthreads();
  }
  int base = s_cnt[tid] - cnt;
  #pragma unroll
  for (int k = 0; k < 16; ++k) {
    pos[s0 + k] = keep[k] ? base : -1;
    base += keep[k];
  }
  if (tid == 255) meta[0] = s_cnt[255];
}

// ---------------- fused QKV projection GEMM (32x32x16 MFMA) ----------------
__global__ __launch_bounds__(256) void k_qkv(
    const f16* __restrict__ xb, const f16* __restrict__ wqkv,
    const float* __restrict__ bq, const float* __restrict__ bk, const float* __restrict__ bv,
    const int* __restrict__ pos,
    f16* __restrict__ Qh, f16* __restrict__ Kc, f16* __restrict__ Vrow) {
  __shared__ __attribute__((aligned(16))) f16 lA[128 * 32];
  __shared__ __attribute__((aligned(16))) f16 lB[128 * 32];
  const int tid = threadIdx.x;
  const int wid = tid >> 6, lane = tid & 63;
  const int hf = lane >> 5, l31 = lane & 31;
  const int wm = wid >> 1, wn = wid & 1;
  const int tn = blockIdx.x;
  const int m0 = blockIdx.y * 128;
  const int mat = tn / 6;
  const int nb = (tn % 6) * 128;
  const f16* wbase = wqkv + (size_t)mat * HDIM * HDIM;

  f32x16 acc[2][2] = {};

  for (int k0 = 0; k0 < HDIM; k0 += 32) {
    #pragma unroll
    for (int iss = 0; iss < 2; ++iss) {
      int c = iss * 256 + tid;
      int row = c >> 2, slot = c & 3;
      int gs = slot ^ swz4(row);
      async_copy16((const char*)(xb + (size_t)(m0 + row) * HDIM + k0) + gs * 16,
                   (char*)lA + (iss * 256 + wid * 64) * 16);
      async_copy16((const char*)(wbase + (size_t)(nb + row) * HDIM + k0) + gs * 16,
                   (char*)lB + (iss * 256 + wid * 64) * 16);
    }
    __syncthreads();
    #pragma unroll
    for (int kk = 0; kk < 2; ++kk) {
      f16x8 af[2], bf[2];
      #pragma unroll
      for (int mi = 0; mi < 2; ++mi) {
        int row = wm * 64 + mi * 32 + l31;
        af[mi] = *(const f16x8*)&lA[row * 32 + (((kk * 2 + hf) ^ swz4(row)) * 8)];
      }
      #pragma unroll
      for (int ni = 0; ni < 2; ++ni) {
        int row = wn * 64 + ni * 32 + l31;
        bf[ni] = *(const f16x8*)&lB[row * 32 + (((kk * 2 + hf) ^ swz4(row)) * 8)];
      }
      #pragma unroll
      for (int mi = 0; mi < 2; ++mi)
        #pragma unroll
        for (int ni = 0; ni < 2; ++ni)
          acc[mi][ni] = __builtin_amdgcn_mfma_f32_32x32x16_f16(af[mi], bf[ni], acc[mi][ni], 0, 0, 0);
    }
    __syncthreads();
  }

  const float* bias = (mat == 0) ? bq : (mat == 1) ? bk : bv;
  const float qscale = 0.125f * 1.44269504088896341f;  // 1/sqrt(64) * log2(e)
  f16* kvdst = (mat == 1) ? Kc : Vrow;
  #pragma unroll
  for (int mi = 0; mi < 2; ++mi) {
    #pragma unroll
    for (int ni = 0; ni < 2; ++ni) {
      int n = nb + wn * 64 + ni * 32 + l31;
      int head = n >> 6, d = n & 63;
      float b = bias[n];
      #pragma unroll
      for (int reg = 0; reg < 16; ++reg) {
        int s = m0 + wm * 64 + mi * 32 + (reg & 3) + 8 * (reg >> 2) + 4 * hf;
        float val = acc[mi][ni][reg] + b;
        if (mat == 0) {
          Qh[((size_t)head * S_LEN + s) * DHEAD + d] = (f16)(val * qscale);
        } else {
          int p = pos[s];
          if (p >= 0)
            kvdst[((size_t)head * S_LEN + p) * DHEAD + d] = (f16)val;
        }
      }
    }
  }
}

// ---------------- V transpose [h][p][d] -> [h][d][rho] (key bits 2<->3 swapped) ----------
// Also zeroes the K pad rows [kc, kcp) for this head (boundary block only).
__global__ __launch_bounds__(256) void k_vt(const int* __restrict__ meta,
                                            const f16* __restrict__ Vrow,
                                            f16* __restrict__ Vtc,
                                            f16* __restrict__ Kc) {
  const int kc = meta[0];
  const int kcp = (kc + 63) & ~63;
  const int p0 = blockIdx.x * 64;
  const int h = blockIdx.y;
  const int tid = threadIdx.x;
  if (p0 >= kcp) return;
  // zero K pad rows (exactly the block whose range contains kc, when kc%64 != 0)
  if (p0 <= kc && kc < p0 + 64 && kc < kcp) {
    const int npad = kcp - kc;
    for (int u = tid; u < npad * 8; u += 256) {
      int r = kc + (u >> 3), c8 = u & 7;
      f16x8 z = {};
      *(f16x8*)&Kc[((size_t)h * S_LEN + r) * DHEAD + c8 * 8] = z;
    }
  }
  __shared__ __attribute__((aligned(16))) f16 lT[64 * 80];   // [d][p], stride 80
  for (int u = tid; u < 512; u += 256) {
    int d8 = u >> 6, p = u & 63;
    f16x8 v = {};
    if (p0 + p < kc) v = *(const f16x8*)&Vrow[((size_t)h * S_LEN + p0 + p) * DHEAD + d8 * 8];
    #pragma unroll
    for (int j = 0; j < 8; ++j) lT[(d8 * 8 + j) * 80 + p] = v[j];
  }
  __syncthreads();
  for (int w = tid; w < 512; w += 256) {
    int d = w >> 3, p8 = w & 7;
    int base16 = (p8 >> 1) * 16, half = p8 & 1;
    f16x4 lo = *(const f16x4*)&lT[d * 80 + base16 + half * 4];
    f16x4 hi = *(const f16x4*)&lT[d * 80 + base16 + 8 + half * 4];
    f16x8 o;
    o[0] = lo[0]; o[1] = lo[1]; o[2] = lo[2]; o[3] = lo[3];
    o[4] = hi[0]; o[5] = hi[1]; o[6] = hi[2]; o[7] = hi[3];
    *(f16x8*)&Vtc[((size_t)h * DHEAD + d) * S_LEN + p0 + p8 * 8] = o;
  }
}

// ---------------- flash attention: 32q/wave, register-P, 4-way key split ----------------
// grid (32 q-tiles of 128, 12 heads, 4 key-splits) = 1536 blocks = 6 blocks/CU,
// 24 waves/CU: cross-block wave overlap hides the per-block barrier stalls.
__global__ __launch_bounds__(256, 4) void k_attn(
    const f16* __restrict__ Qh, const f16* __restrict__ Kc, const f16* __restrict__ Vtc,
    const int* __restrict__ meta, f16* __restrict__ POb, float* __restrict__ PL) {
  __shared__ __attribute__((aligned(16))) f16 lK[64 * 64];   // [key][d] swizzled, 8KB
  __shared__ __attribute__((aligned(16))) f16 lV[64 * 64];   // [d][rho] swizzled, 8KB
  const int tid = threadIdx.x;
  const int wid = tid >> 6, lane = tid & 63;
  const int hf = lane >> 5, l31 = lane & 31, r7 = l31 & 7;
  const int head = blockIdx.y;
  const int split = blockIdx.z;
  const int q0 = blockIdx.x * 128 + wid * 32;
  const int kc = meta[0];
  const int nkt = (kc + 63) >> 6;
  const int t0 = (split * nkt) >> 2;
  const int t1 = ((split + 1) * nkt) >> 2;

  // Q B-frags: lane n = q = l31, k = dc*16 + hf*8 + j  (held in regs whole kernel)
  const f16* Qp = Qh + ((size_t)head * S_LEN + q0 + l31) * DHEAD;
  f16x8 qf[4];
  #pragma unroll
  for (int dc = 0; dc < 4; ++dc) qf[dc] = *(const f16x8*)(Qp + dc * 16 + hf * 8);

  f32x16 accO[2] = {};     // [dh]: O columns dh*32+l31, rows = C-layout
  float lsum = 0.f;

  const char* kbase = (const char*)(Kc + (size_t)head * S_LEN * DHEAD);
  const char* vbase = (const char*)(Vtc + (size_t)head * DHEAD * S_LEN);

  for (int t = t0; t < t1; ++t) {
    const int j0 = t * 64;
    #pragma unroll
    for (int iss = 0; iss < 2; ++iss) {
      int c = iss * 256 + tid;                 // 0..511 chunk id
      int row = c >> 3, slot = c & 7;
      int gs = slot ^ (row & 7);               // 8x16B-slot XOR swizzle
      async_copy16(kbase + (size_t)(j0 + row) * 128 + gs * 16,
                   (char*)lK + (iss * 256 + wid * 64) * 16);
      async_copy16(vbase + (size_t)row * (S_LEN * 2) + (size_t)j0 * 2 + gs * 16,
                   (char*)lV + (iss * 256 + wid * 64) * 16);
    }
    __syncthreads();

    #pragma unroll
    for (int mh = 0; mh < 2; ++mh) {
      // K A-frags: lane m = key = mh*32 + l31, k = dc*16 + hf*8 + j
      f16x8 af[4];
      const int arow = mh * 32 + l31;
      #pragma unroll
      for (int dc = 0; dc < 4; ++dc)
        af[dc] = *(const f16x8*)&lK[arow * 64 + ((((dc << 1) | hf) ^ r7) * 8)];
      f32x16 s = {};
      #pragma unroll
      for (int dc = 0; dc < 4; ++dc)
        s = __builtin_amdgcn_mfma_f32_32x32x16_f16(af[dc], qf[dc], s, 0, 0, 0);
      #pragma unroll
      for (int u = 0; u < 16; ++u) { s[u] = fast_exp2(s[u]); lsum += s[u]; }
      // PV: A-frag for 16-key chunk c2 = own C-regs [8cc..8cc+7] (V key-permuted)
      #pragma unroll
      for (int cc = 0; cc < 2; ++cc) {
        f16x8 pf;
        #pragma unroll
        for (int u = 0; u < 8; ++u) pf[u] = (f16)s[8 * cc + u];
        const int c2 = mh * 2 + cc;
        #pragma unroll
        for (int dh = 0; dh < 2; ++dh) {
          const int vrow = dh * 32 + l31;
          f16x8 vf = *(const f16x8*)&lV[vrow * 64 + ((((c2 << 1) | hf) ^ r7) * 8)];
          accO[dh] = __builtin_amdgcn_mfma_f32_32x32x16_f16(pf, vf, accO[dh], 0, 0, 0);
        }
      }
    }
    __syncthreads();
  }

  // fold hf halves (each lane summed only 32 of the 64 key-rows per tile)
  lsum += __shfl_xor(lsum, 32);
  // pad keys are zero K rows -> P = 1 exactly; last tile lives in split 3
  if (split == NSPLIT - 1) lsum -= (float)(nkt * 64 - kc);
  if (hf == 0)
    PL[((size_t)split * NHEAD + head) * S_LEN + q0 + l31] = lsum;

  f16* PO = POb + (size_t)split * NHEAD * S_LEN * DHEAD;
  #pragma unroll
  for (int dh = 0; dh < 2; ++dh)
    #pragma unroll
    for (int reg = 0; reg < 16; ++reg) {
      int row = (reg & 3) + 8 * (reg >> 2) + 4 * hf;
      PO[((size_t)head * S_LEN + q0 + row) * DHEAD + dh * 32 + l31] = (f16)accO[dh][reg];
    }
}

// ---------------- output projection GEMM, fused 4-way combine (fp32 out) ----------------
__global__ __launch_bounds__(256) void k_out(
    const f16* __restrict__ POb, const float* __restrict__ PL,
    const f16* __restrict__ wo, const float* __restrict__ bo, float* __restrict__ out) {
  __shared__ __attribute__((aligned(16))) f16 lA[128 * 32];
  __shared__ __attribute__((aligned(16))) f16 lB[128 * 32];
  __shared__ float linv[NHEAD * 128];
  const int tid = threadIdx.x;
  const int wid = tid >> 6, lane = tid & 63;
  const int hf = lane >> 5, l31 = lane & 31;
  const int wm = wid >> 1, wn = wid & 1;
  const int nb = blockIdx.x * 128;
  const int m0 = blockIdx.y * 128;
  constexpr size_t POSTRIDE = (size_t)NHEAD * S_LEN * DHEAD;

  // per-block 1/l table: 12 heads x 128 rows
  for (int i = tid; i < NHEAD * 128; i += 256) {
    int h = i >> 7, r = i & 127;
    float l = 0.f;
    #pragma unroll
    for (int sp = 0; sp < NSPLIT; ++sp)
      l += PL[((size_t)sp * NHEAD + h) * S_LEN + m0 + r];
    linv[i] = 1.0f / l;
  }
  __syncthreads();

  f32x16 acc[2][2] = {};

  for (int k0 = 0; k0 < HDIM; k0 += 32) {
    const int head = k0 >> 6, d0 = k0 & 63;
    #pragma unroll
    for (int iss = 0; iss < 2; ++iss) {
      int c = iss * 256 + tid;
      int row = c >> 2, slot = c & 3;
      int gs = slot ^ swz4(row);
      // A: combine PO splits, scale by 1/l, write to LDS chunk c
      size_t pi = ((size_t)head * S_LEN + m0 + row) * DHEAD + d0 + gs * 8;
      float sum[8] = {};
      #pragma unroll
      for (int sp = 0; sp < NSPLIT; ++sp) {
        f16x8 a = *(const f16x8*)(POb + sp * POSTRIDE + pi);
        #pragma unroll
        for (int u = 0; u < 8; ++u) sum[u] += (float)a[u];
      }
      float il = linv[head * 128 + row];
      f16x8 av;
      #pragma unroll
      for (int u = 0; u < 8; ++u) av[u] = (f16)(sum[u] * il);
      *(f16x8*)&lA[c * 8] = av;
      // B: weights via async copy
      async_copy16((const char*)(wo + (size_t)(nb + row) * HDIM + k0) + gs * 16,
                   (char*)lB + (iss * 256 + wid * 64) * 16);
    }
    __syncthreads();
    #pragma unroll
    for (int kk = 0; kk < 2; ++kk) {
      f16x8 af[2], bf[2];
      #pragma unroll
      for (int mi = 0; mi < 2; ++mi) {
        int row = wm * 64 + mi * 32 + l31;
        af[mi] = *(const f16x8*)&lA[row * 32 + (((kk * 2 + hf) ^ swz4(row)) * 8)];
      }
      #pragma unroll
      for (int ni = 0; ni < 2; ++ni) {
        int row = wn * 64 + ni * 32 + l31;
        bf[ni] = *(const f16x8*)&lB[row * 32 + (((kk * 2 + hf) ^ swz4(row)) * 8)];
      }
      #pragma unroll
      for (int mi = 0; mi < 2; ++mi)
        #pragma unroll
        for (int ni = 0; ni < 2; ++ni)
          acc[mi][ni] = __builtin_amdgcn_mfma_f32_32x32x16_f16(af[mi], bf[ni], acc[mi][ni], 0, 0, 0);
    }
    __syncthreads();
  }

  #pragma unroll
  for (int mi = 0; mi < 2; ++mi) {
    #pragma unroll
    for (int ni = 0; ni < 2; ++ni) {
      int n = nb + wn * 64 + ni * 32 + l31;
      float b = bo[n];
      #pragma unroll
      for (int reg = 0; reg < 16; ++reg) {
        int s = m0 + wm * 64 + mi * 32 + (reg & 3) + 8 * (reg >> 2) + 4 * hf;
        out[(size_t)s * HDIM + n] = acc[mi][ni][reg] + b;
      }
    }
  }
}

extern "C" void kernel_launch(void* const* d_in, const int* in_sizes, int n_in,
                              void* d_out, int out_size, void* d_ws, size_t ws_size,
                              hipStream_t stream) {
  const float* x  = (const float*)d_in[0];
  const float* Wq = (const float*)d_in[1];
  const float* bq = (const float*)d_in[2];
  const float* Wk = (const float*)d_in[3];
  const float* bk = (const float*)d_in[4];
  const float* Wv = (const float*)d_in[5];
  const float* bv = (const float*)d_in[6];
  const float* Wo = (const float*)d_in[7];
  const float* bo = (const float*)d_in[8];
  const int*   mask = (const int*)d_in[9];
  float* out = (float*)d_out;

  char* ws = (char*)d_ws;
  int* meta  = (int*)(ws + OFF_META);
  int* pos   = (int*)(ws + OFF_POS);
  f16* xb    = (f16*)(ws + OFF_XB);
  f16* wqkv  = (f16*)(ws + OFF_WQKV);
  f16* wob   = (f16*)(ws + OFF_WO);
  f16* Qh    = (f16*)(ws + OFF_Q);
  f16* Kc    = (f16*)(ws + OFF_K);
  f16* Vtc   = (f16*)(ws + OFF_VT);
  f16* Vrow  = (f16*)(ws + OFF_VR);
  f16* POb   = (f16*)(ws + OFF_VR);     // PO splits 0..3 start here (split0 reuses Vrow)
  float* PL  = (float*)(ws + OFF_WQKV); // reuses wqkv after k_qkv

  k_prep<<<dim3(5377), 256, 0, stream>>>(x, Wq, Wk, Wv, Wo, mask, xb, pos, meta);
  k_qkv<<<dim3(18, 32), 256, 0, stream>>>(xb, wqkv, bq, bk, bv, pos, Qh, Kc, Vrow);
  k_vt<<<dim3(64, NHEAD), 256, 0, stream>>>(meta, Vrow, Vtc, Kc);
  k_attn<<<dim3(32, NHEAD, NSPLIT), 256, 0, stream>>>(Qh, Kc, Vtc, meta, POb, PL);
  k_out<<<dim3(6, 32), 256, 0, stream>>>(POb, PL, wob, bo, out);
}

// Round 11
// 182.237 us; speedup vs baseline: 1.1211x; 1.1211x over previous
//
#include <hip/hip_runtime.h>
#include <stdint.h>

#define S_LEN 4096
#define HDIM  768
#define NHEAD 12
#define DHEAD 64

typedef _Float16 f16;
typedef __attribute__((ext_vector_type(8)))  _Float16 f16x8;
typedef __attribute__((ext_vector_type(4)))  _Float16 f16x4;
typedef __attribute__((ext_vector_type(4)))  float    f32x4;
typedef __attribute__((ext_vector_type(16))) float    f32x16;

typedef __attribute__((address_space(1))) void gv_t;
typedef __attribute__((address_space(3))) void lv_t;

__device__ __forceinline__ void async_copy16(const void* g, void* l) {
  __builtin_amdgcn_global_load_lds((gv_t*)g, (lv_t*)l, 16, 0, 0);
}

__device__ __forceinline__ float fast_exp2(float x) {
#if __has_builtin(__builtin_amdgcn_exp2f)
  return __builtin_amdgcn_exp2f(x);
#else
  return exp2f(x);
#endif
}

__device__ __forceinline__ int swz4(int row) { return (row ^ (row >> 2)) & 3; }

// ---------------- workspace layout (heavy reuse) ----------------
constexpr size_t OFF_META = 0;                          // int kcount
constexpr size_t OFF_RIDX = 256;                        // int[4096] inverse map p->s
constexpr size_t OFF_XB   = 65536;                      // f16 x[4096*768]
constexpr size_t SZ_XB    = (size_t)S_LEN * HDIM * 2;
constexpr size_t OFF_WQKV = OFF_XB + SZ_XB;             // f16[3*768*768]; later PL
constexpr size_t SZ_WQKV  = (size_t)3 * HDIM * HDIM * 2;
constexpr size_t OFF_WO   = OFF_WQKV + SZ_WQKV;         // f16[768*768]
constexpr size_t SZ_WO    = (size_t)HDIM * HDIM * 2;
constexpr size_t OFF_Q    = OFF_WO + SZ_WO;             // f16[12][4096][64]
constexpr size_t SZ_HD    = (size_t)NHEAD * S_LEN * DHEAD * 2;
constexpr size_t OFF_K    = OFF_Q + SZ_HD;              // f16[12][4096][64] compacted
constexpr size_t OFF_VT   = OFF_K + SZ_HD;              // f16[12][64][4096] transposed+permuted V
constexpr size_t OFF_VR   = OFF_VT + SZ_HD;             // f16[12][4096][64] V rows; later PO split0
constexpr size_t OFF_PO1  = OFF_VR + SZ_HD;             // f16[12][4096][64] PO split1

// ---------------- prep: fp32->fp16 convert + mask compaction (inverse map) ----------------
__global__ __launch_bounds__(256) void k_prep(const float* __restrict__ x,
                                              const float* __restrict__ wq,
                                              const float* __restrict__ wk,
                                              const float* __restrict__ wv,
                                              const float* __restrict__ wo,
                                              const int* __restrict__ mi,
                                              f16* __restrict__ dst,
                                              int* __restrict__ ridx,
                                              int* __restrict__ meta) {
  __shared__ int s_flag;
  __shared__ int s_cnt[256];
  const int b = blockIdx.x, tid = threadIdx.x;
  if (b < 5376) {
    int i = b * 256 + tid;                   // 1376256 float4 units
    const float* src; int off;
    if (i < 786432) { src = x; off = i; }
    else {
      int j = i - 786432;
      int w = j / 147456;
      off = j - w * 147456;
      src = (w == 0) ? wq : (w == 1) ? wk : (w == 2) ? wv : wo;
    }
    float4 v = ((const float4*)src)[off];
    f16x4 h;
    h[0] = (f16)v.x; h[1] = (f16)v.y; h[2] = (f16)v.z; h[3] = (f16)v.w;
    ((f16x4*)dst)[i] = h;
    return;
  }
  // ---- mask block ----
  if (tid == 0) s_flag = 1;
  __syncthreads();
  int bad = 0;
  #pragma unroll
  for (int k = 0; k < 4; ++k) {
    int v = mi[k * 256 + tid];
    if (v != 0 && v != 1) bad = 1;
  }
  if (bad) atomicAnd(&s_flag, 0);
  __syncthreads();
  const int isInt = s_flag;
  const unsigned char* mu8 = (const unsigned char*)mi;
  int keep[16]; int cnt = 0;
  const int s0 = tid * 16;
  #pragma unroll
  for (int k = 0; k < 16; ++k) {
    int mval = isInt ? mi[s0 + k] : (int)mu8[s0 + k];
    keep[k] = (mval == 0) ? 1 : 0;           // True => masked out (excluded)
    cnt += keep[k];
    ridx[s0 + k] = 0;                        // zero-fill inverse map (pad-safe)
  }
  s_cnt[tid] = cnt;
  __syncthreads();
  for (int off = 1; off < 256; off <<= 1) {
    int t = (tid >= off) ? s_cnt[tid - off] : 0;
    __syncthreads();
    s_cnt[tid] += t;
    __syncthreads();
  }
  int base = s_cnt[tid] - cnt;               // exclusive prefix
  #pragma unroll
  for (int k = 0; k < 16; ++k) {
    if (keep[k]) { ridx[base] = s0 + k; ++base; }
  }
  if (tid == 255) meta[0] = s_cnt[255];
}

// ---------------- fused QKV projection GEMM (32x32x16 MFMA, compacted K/V rows) ---------
// Q tiles compute all 4096 rows. K/V tiles compute ONLY the ~kc kept rows, gathering
// their A-rows from x via ridx (inverse compaction map) — ~33% less GEMM work.
__global__ __launch_bounds__(256) void k_qkv(
    const f16* __restrict__ xb, const f16* __restrict__ wqkv,
    const float* __restrict__ bq, const float* __restrict__ bk, const float* __restrict__ bv,
    const int* __restrict__ ridx, const int* __restrict__ meta,
    f16* __restrict__ Qh, f16* __restrict__ Kc, f16* __restrict__ Vrow) {
  __shared__ __attribute__((aligned(16))) f16 lA[128 * 32];
  __shared__ __attribute__((aligned(16))) f16 lB[128 * 32];
  const int tid = threadIdx.x;
  const int wid = tid >> 6, lane = tid & 63;
  const int hf = lane >> 5, l31 = lane & 31;
  const int wm = wid >> 1, wn = wid & 1;
  const int tn = blockIdx.x;
  const int m0 = blockIdx.y * 128;
  const int mat = tn / 6;
  const int nb = (tn % 6) * 128;
  const int kc = meta[0];
  if (mat != 0 && m0 >= kc) return;          // fully-pad K/V tile
  const f16* wbase = wqkv + (size_t)mat * HDIM * HDIM;

  // per-thread A source rows (chunks c = tid and c = tid+256)
  const int ar0 = tid >> 2, ar1 = 64 + (tid >> 2);
  const f16* asrc0;
  const f16* asrc1;
  if (mat == 0) {
    asrc0 = xb + (size_t)(m0 + ar0) * HDIM;
    asrc1 = xb + (size_t)(m0 + ar1) * HDIM;
  } else {
    int g0 = (m0 + ar0 < kc) ? ridx[m0 + ar0] : 0;
    int g1 = (m0 + ar1 < kc) ? ridx[m0 + ar1] : 0;
    asrc0 = xb + (size_t)g0 * HDIM;
    asrc1 = xb + (size_t)g1 * HDIM;
  }
  const int slot = tid & 3;
  const int gs0 = slot ^ swz4(ar0);
  const int gs1 = slot ^ swz4(ar1);

  f32x16 acc[2][2] = {};

  for (int k0 = 0; k0 < HDIM; k0 += 32) {
    async_copy16((const char*)(asrc0 + k0) + gs0 * 16, (char*)lA + (wid * 64) * 16);
    async_copy16((const char*)(asrc1 + k0) + gs1 * 16, (char*)lA + (256 + wid * 64) * 16);
    async_copy16((const char*)(wbase + (size_t)(nb + ar0) * HDIM + k0) + gs0 * 16,
                 (char*)lB + (wid * 64) * 16);
    async_copy16((const char*)(wbase + (size_t)(nb + ar1) * HDIM + k0) + gs1 * 16,
                 (char*)lB + (256 + wid * 64) * 16);
    __syncthreads();
    #pragma unroll
    for (int kk = 0; kk < 2; ++kk) {
      f16x8 af[2], bf[2];
      #pragma unroll
      for (int mi = 0; mi < 2; ++mi) {
        int row = wm * 64 + mi * 32 + l31;
        af[mi] = *(const f16x8*)&lA[row * 32 + (((kk * 2 + hf) ^ swz4(row)) * 8)];
      }
      #pragma unroll
      for (int ni = 0; ni < 2; ++ni) {
        int row = wn * 64 + ni * 32 + l31;
        bf[ni] = *(const f16x8*)&lB[row * 32 + (((kk * 2 + hf) ^ swz4(row)) * 8)];
      }
      #pragma unroll
      for (int mi = 0; mi < 2; ++mi)
        #pragma unroll
        for (int ni = 0; ni < 2; ++ni)
          acc[mi][ni] = __builtin_amdgcn_mfma_f32_32x32x16_f16(af[mi], bf[ni], acc[mi][ni], 0, 0, 0);
    }
    __syncthreads();
  }

  const float* bias = (mat == 0) ? bq : (mat == 1) ? bk : bv;
  const float qscale = 0.125f * 1.44269504088896341f;  // 1/sqrt(64) * log2(e)
  f16* kvdst = (mat == 1) ? Kc : Vrow;
  #pragma unroll
  for (int mi = 0; mi < 2; ++mi) {
    #pragma unroll
    for (int ni = 0; ni < 2; ++ni) {
      int n = nb + wn * 64 + ni * 32 + l31;
      int head = n >> 6, d = n & 63;
      float b = bias[n];
      #pragma unroll
      for (int reg = 0; reg < 16; ++reg) {
        int s = m0 + wm * 64 + mi * 32 + (reg & 3) + 8 * (reg >> 2) + 4 * hf;
        float val = acc[mi][ni][reg] + b;
        if (mat == 0) {
          Qh[((size_t)head * S_LEN + s) * DHEAD + d] = (f16)(val * qscale);
        } else if (s < kc) {
          kvdst[((size_t)head * S_LEN + s) * DHEAD + d] = (f16)val;
        }
      }
    }
  }
}

// ---------------- V transpose [h][p][d] -> [h][d][rho] (key bits 2<->3 swapped) ----------
// Also zeroes the K pad rows [kc, kcp) for this head (boundary block only).
__global__ __launch_bounds__(256) void k_vt(const int* __restrict__ meta,
                                            const f16* __restrict__ Vrow,
                                            f16* __restrict__ Vtc,
                                            f16* __restrict__ Kc) {
  const int kc = meta[0];
  const int kcp = (kc + 63) & ~63;
  const int p0 = blockIdx.x * 64;
  const int h = blockIdx.y;
  const int tid = threadIdx.x;
  if (p0 >= kcp) return;
  // zero K pad rows (exactly the block whose range contains kc, when kc%64 != 0)
  if (p0 <= kc && kc < p0 + 64 && kc < kcp) {
    const int npad = kcp - kc;
    for (int u = tid; u < npad * 8; u += 256) {
      int r = kc + (u >> 3), c8 = u & 7;
      f16x8 z = {};
      *(f16x8*)&Kc[((size_t)h * S_LEN + r) * DHEAD + c8 * 8] = z;
    }
  }
  __shared__ __attribute__((aligned(16))) f16 lT[64 * 80];   // [d][p], stride 80
  for (int u = tid; u < 512; u += 256) {
    int d8 = u >> 6, p = u & 63;
    f16x8 v = {};
    if (p0 + p < kc) v = *(const f16x8*)&Vrow[((size_t)h * S_LEN + p0 + p) * DHEAD + d8 * 8];
    #pragma unroll
    for (int j = 0; j < 8; ++j) lT[(d8 * 8 + j) * 80 + p] = v[j];
  }
  __syncthreads();
  for (int w = tid; w < 512; w += 256) {
    int d = w >> 3, p8 = w & 7;
    int base16 = (p8 >> 1) * 16, half = p8 & 1;
    f16x4 lo = *(const f16x4*)&lT[d * 80 + base16 + half * 4];
    f16x4 hi = *(const f16x4*)&lT[d * 80 + base16 + 8 + half * 4];
    f16x8 o;
    o[0] = lo[0]; o[1] = lo[1]; o[2] = lo[2]; o[3] = lo[3];
    o[4] = hi[0]; o[5] = hi[1]; o[6] = hi[2]; o[7] = hi[3];
    *(f16x8*)&Vtc[((size_t)h * DHEAD + d) * S_LEN + p0 + p8 * 8] = o;
  }
}

// ---------------- flash attention: 32q/wave, register-P, shared K/V tile (r7 best) -------
__global__ __launch_bounds__(256, 3) void k_attn(
    const f16* __restrict__ Qh, const f16* __restrict__ Kc, const f16* __restrict__ Vtc,
    const int* __restrict__ meta, f16* __restrict__ PO0, f16* __restrict__ PO1,
    float* __restrict__ PL) {
  __shared__ __attribute__((aligned(16))) f16 lK[64 * 64];   // [key][d] swizzled, 8KB
  __shared__ __attribute__((aligned(16))) f16 lV[64 * 64];   // [d][rho] swizzled, 8KB
  const int tid = threadIdx.x;
  const int wid = tid >> 6, lane = tid & 63;
  const int hf = lane >> 5, l31 = lane & 31, r7 = l31 & 7;
  const int head = blockIdx.y;
  const int split = blockIdx.z;
  const int q0 = blockIdx.x * 128 + wid * 32;
  const int kc = meta[0];
  const int nkt = (kc + 63) >> 6;
  const int th = nkt >> 1;
  const int t0 = split ? th : 0;
  const int t1 = split ? nkt : th;

  // Q B-frags: lane n = q = l31, k = dc*16 + hf*8 + j  (held in regs whole kernel)
  const f16* Qp = Qh + ((size_t)head * S_LEN + q0 + l31) * DHEAD;
  f16x8 qf[4];
  #pragma unroll
  for (int dc = 0; dc < 4; ++dc) qf[dc] = *(const f16x8*)(Qp + dc * 16 + hf * 8);

  f32x16 accO[2] = {};     // [dh]: O columns dh*32+l31, rows = C-layout
  float lsum = 0.f;

  const char* kbase = (const char*)(Kc + (size_t)head * S_LEN * DHEAD);
  const char* vbase = (const char*)(Vtc + (size_t)head * DHEAD * S_LEN);

  for (int t = t0; t < t1; ++t) {
    const int j0 = t * 64;
    #pragma unroll
    for (int iss = 0; iss < 2; ++iss) {
      int c = iss * 256 + tid;                 // 0..511 chunk id
      int row = c >> 3, slot = c & 7;
      int gs = slot ^ (row & 7);               // 8x16B-slot XOR swizzle
      async_copy16(kbase + (size_t)(j0 + row) * 128 + gs * 16,
                   (char*)lK + (iss * 256 + wid * 64) * 16);
      async_copy16(vbase + (size_t)row * (S_LEN * 2) + (size_t)j0 * 2 + gs * 16,
                   (char*)lV + (iss * 256 + wid * 64) * 16);
    }
    __syncthreads();

    #pragma unroll
    for (int mh = 0; mh < 2; ++mh) {
      // K A-frags: lane m = key = mh*32 + l31, k = dc*16 + hf*8 + j
      f16x8 af[4];
      const int arow = mh * 32 + l31;
      #pragma unroll
      for (int dc = 0; dc < 4; ++dc)
        af[dc] = *(const f16x8*)&lK[arow * 64 + ((((dc << 1) | hf) ^ r7) * 8)];
      f32x16 s = {};
      #pragma unroll
      for (int dc = 0; dc < 4; ++dc)
        s = __builtin_amdgcn_mfma_f32_32x32x16_f16(af[dc], qf[dc], s, 0, 0, 0);
      #pragma unroll
      for (int u = 0; u < 16; ++u) { s[u] = fast_exp2(s[u]); lsum += s[u]; }
      // PV: A-frag for 16-key chunk c2 = own C-regs [8cc..8cc+7] (V key-permuted)
      #pragma unroll
      for (int cc = 0; cc < 2; ++cc) {
        f16x8 pf;
        #pragma unroll
        for (int u = 0; u < 8; ++u) pf[u] = (f16)s[8 * cc + u];
        const int c2 = mh * 2 + cc;
        #pragma unroll
        for (int dh = 0; dh < 2; ++dh) {
          const int vrow = dh * 32 + l31;
          f16x8 vf = *(const f16x8*)&lV[vrow * 64 + ((((c2 << 1) | hf) ^ r7) * 8)];
          accO[dh] = __builtin_amdgcn_mfma_f32_32x32x16_f16(pf, vf, accO[dh], 0, 0, 0);
        }
      }
    }
    __syncthreads();
  }

  // fold hf halves (each lane summed only 32 of the 64 key-rows per tile)
  lsum += __shfl_xor(lsum, 32);
  // pad keys are zero K rows -> P = 1 exactly; last tile lives in split 1
  if (split == 1) lsum -= (float)(nkt * 64 - kc);
  if (hf == 0)
    PL[((size_t)split * NHEAD + head) * S_LEN + q0 + l31] = lsum;

  f16* PO = split ? PO1 : PO0;
  #pragma unroll
  for (int dh = 0; dh < 2; ++dh)
    #pragma unroll
    for (int reg = 0; reg < 16; ++reg) {
      int row = (reg & 3) + 8 * (reg >> 2) + 4 * hf;
      PO[((size_t)head * S_LEN + q0 + row) * DHEAD + dh * 32 + l31] = (f16)accO[dh][reg];
    }
}

// ---------------- output projection GEMM, fused split-combine (fp32 out) ----------------
__global__ __launch_bounds__(256) void k_out(
    const f16* __restrict__ PO0, const f16* __restrict__ PO1,
    const float* __restrict__ PL, const f16* __restrict__ wo,
    const float* __restrict__ bo, float* __restrict__ out) {
  __shared__ __attribute__((aligned(16))) f16 lA[128 * 32];
  __shared__ __attribute__((aligned(16))) f16 lB[128 * 32];
  __shared__ float linv[NHEAD * 128];
  const int tid = threadIdx.x;
  const int wid = tid >> 6, lane = tid & 63;
  const int hf = lane >> 5, l31 = lane & 31;
  const int wm = wid >> 1, wn = wid & 1;
  const int nb = blockIdx.x * 128;
  const int m0 = blockIdx.y * 128;

  // per-block 1/l table: 12 heads x 128 rows
  for (int i = tid; i < NHEAD * 128; i += 256) {
    int h = i >> 7, r = i & 127;
    float l = PL[(size_t)h * S_LEN + m0 + r] + PL[(size_t)(NHEAD + h) * S_LEN + m0 + r];
    linv[i] = 1.0f / l;
  }
  __syncthreads();

  f32x16 acc[2][2] = {};

  for (int k0 = 0; k0 < HDIM; k0 += 32) {
    const int head = k0 >> 6, d0 = k0 & 63;
    #pragma unroll
    for (int iss = 0; iss < 2; ++iss) {
      int c = iss * 256 + tid;
      int row = c >> 2, slot = c & 3;
      int gs = slot ^ swz4(row);
      // A: combine PO splits, scale by 1/l, write to LDS chunk c
      size_t pi = ((size_t)head * S_LEN + m0 + row) * DHEAD + d0 + gs * 8;
      f16x8 a0 = *(const f16x8*)(PO0 + pi);
      f16x8 a1 = *(const f16x8*)(PO1 + pi);
      float il = linv[head * 128 + row];
      f16x8 av;
      #pragma unroll
      for (int u = 0; u < 8; ++u) av[u] = (f16)(((float)a0[u] + (float)a1[u]) * il);
      *(f16x8*)&lA[c * 8] = av;
      // B: weights via async copy
      async_copy16((const char*)(wo + (size_t)(nb + row) * HDIM + k0) + gs * 16,
                   (char*)lB + (iss * 256 + wid * 64) * 16);
    }
    __syncthreads();
    #pragma unroll
    for (int kk = 0; kk < 2; ++kk) {
      f16x8 af[2], bf[2];
      #pragma unroll
      for (int mi = 0; mi < 2; ++mi) {
        int row = wm * 64 + mi * 32 + l31;
        af[mi] = *(const f16x8*)&lA[row * 32 + (((kk * 2 + hf) ^ swz4(row)) * 8)];
      }
      #pragma unroll
      for (int ni = 0; ni < 2; ++ni) {
        int row = wn * 64 + ni * 32 + l31;
        bf[ni] = *(const f16x8*)&lB[row * 32 + (((kk * 2 + hf) ^ swz4(row)) * 8)];
      }
      #pragma unroll
      for (int mi = 0; mi < 2; ++mi)
        #pragma unroll
        for (int ni = 0; ni < 2; ++ni)
          acc[mi][ni] = __builtin_amdgcn_mfma_f32_32x32x16_f16(af[mi], bf[ni], acc[mi][ni], 0, 0, 0);
    }
    __syncthreads();
  }

  #pragma unroll
  for (int mi = 0; mi < 2; ++mi) {
    #pragma unroll
    for (int ni = 0; ni < 2; ++ni) {
      int n = nb + wn * 64 + ni * 32 + l31;
      float b = bo[n];
      #pragma unroll
      for (int reg = 0; reg < 16; ++reg) {
        int s = m0 + wm * 64 + mi * 32 + (reg & 3) + 8 * (reg >> 2) + 4 * hf;
        out[(size_t)s * HDIM + n] = acc[mi][ni][reg] + b;
      }
    }
  }
}

extern "C" void kernel_launch(void* const* d_in, const int* in_sizes, int n_in,
                              void* d_out, int out_size, void* d_ws, size_t ws_size,
                              hipStream_t stream) {
  const float* x  = (const float*)d_in[0];
  const float* Wq = (const float*)d_in[1];
  const float* bq = (const float*)d_in[2];
  const float* Wk = (const float*)d_in[3];
  const float* bk = (const float*)d_in[4];
  const float* Wv = (const float*)d_in[5];
  const float* bv = (const float*)d_in[6];
  const float* Wo = (const float*)d_in[7];
  const float* bo = (const float*)d_in[8];
  const int*   mask = (const int*)d_in[9];
  float* out = (float*)d_out;

  char* ws = (char*)d_ws;
  int* meta  = (int*)(ws + OFF_META);
  int* ridx  = (int*)(ws + OFF_RIDX);
  f16* xb    = (f16*)(ws + OFF_XB);
  f16* wqkv  = (f16*)(ws + OFF_WQKV);
  f16* wob   = (f16*)(ws + OFF_WO);
  f16* Qh    = (f16*)(ws + OFF_Q);
  f16* Kc    = (f16*)(ws + OFF_K);
  f16* Vtc   = (f16*)(ws + OFF_VT);
  f16* Vrow  = (f16*)(ws + OFF_VR);
  f16* PO0   = (f16*)(ws + OFF_VR);     // reuses Vrow after k_vt
  f16* PO1   = (f16*)(ws + OFF_PO1);
  float* PL  = (float*)(ws + OFF_WQKV); // reuses wqkv after k_qkv

  k_prep<<<dim3(5377), 256, 0, stream>>>(x, Wq, Wk, Wv, Wo, mask, xb, ridx, meta);
  k_qkv<<<dim3(18, 32), 256, 0, stream>>>(xb, wqkv, bq, bk, bv, ridx, meta, Qh, Kc, Vrow);
  k_vt<<<dim3(64, NHEAD), 256, 0, stream>>>(meta, Vrow, Vtc, Kc);
  k_attn<<<dim3(32, NHEAD, 2), 256, 0, stream>>>(Qh, Kc, Vtc, meta, PO0, PO1, PL);
  k_out<<<dim3(6, 32), 256, 0, stream>>>(PO0, PO1, PL, wob, bo, out);
}